// Round 4
// baseline (1230.206 us; speedup 1.0000x reference)
//
#include <hip/hip_runtime.h>
#include <hip/hip_bf16.h>

// GCN layer: h = BN(ReLU(segment_sum(norm * (nf@W))[col] + b))
// Aggregate raw features first (agg[c] = sum norm*nf[row]), then GEMM.
// R1: atomic scatter -> CSR gather.
// R2: bf16 feature table, tiled GEMM + fused BN stats, hierarchical scan.
// R3: k_fill (198MB amplified random 8B scatter) -> two-level bucket partition:
//     passA scatters edges to 128-node bucket regions (sequential cursors),
//     passB finalizes CSR order via LDS cursors (L2-hot 32KB window) and
//     fuses degree/dinv (removes k_degw). tab aliases passA tmp buffer.
//
// ws layout (4B words):
//   [0, N)               dinv
//   [N, 2N+1)            ptr (CSR offsets)
//   [2N+1, 3N+1)         cnt (counts -> cursor for fallback fill)
//   [3N+1, 3N+513)       sums (BN: sum, sumsq, scale, shift)
//   [3N+513, 3N+1025)    bsum (scan partials)
//   [3N+1025, +nbuckets) bcur (bucket cursors)
//   [align4]             packed (E x int2: row, w-bits)
//   [align4]             tabtmp: passA tmp (E x int2), later bf16 tab (64N)

__device__ __forceinline__ unsigned bf16rn(float f) {
    unsigned x = __float_as_uint(f);
    return (x + 0x7fffu + ((x >> 16) & 1u)) >> 16;
}
__device__ __forceinline__ float bflo(unsigned u) { return __uint_as_float(u << 16); }
__device__ __forceinline__ float bfhi(unsigned u) { return __uint_as_float(u & 0xffff0000u); }

__global__ void k_init(int* __restrict__ cnt, float* __restrict__ sums, int N) {
    int i = blockIdx.x * 256 + threadIdx.x;
    if (i < N) cnt[i] = 0;
    if (blockIdx.x == 0 && threadIdx.x < 512) sums[threadIdx.x] = 0.0f;
}

__global__ void k_conv(const float* __restrict__ nf, uint4* __restrict__ tab, size_t n8) {
    size_t i = (size_t)blockIdx.x * 256 + threadIdx.x;
    if (i >= n8) return;
    const float4* src = (const float4*)nf;
    float4 a = src[2 * i], b = src[2 * i + 1];
    uint4 r;
    r.x = bf16rn(a.x) | (bf16rn(a.y) << 16);
    r.y = bf16rn(a.z) | (bf16rn(a.w) << 16);
    r.z = bf16rn(b.x) | (bf16rn(b.y) << 16);
    r.w = bf16rn(b.z) | (bf16rn(b.w) << 16);
    tab[i] = r;
}

__global__ void k_count(const int* __restrict__ col, int* __restrict__ cnt, int E) {
    int e = blockIdx.x * 256 + threadIdx.x;
    if (e < E) atomicAdd(&cnt[col[e]], 1);
}

// hierarchical exclusive scan
__global__ __launch_bounds__(256) void kS1(const int* __restrict__ cnt,
                                           int* __restrict__ ptr,
                                           int* __restrict__ bsum, int N) {
    __shared__ int ls[256];
    int t = threadIdx.x, i = blockIdx.x * 256 + t;
    int v = (i < N) ? cnt[i] : 0;
    ls[t] = v;
    __syncthreads();
    for (int off = 1; off < 256; off <<= 1) {
        int u = (t >= off) ? ls[t - off] : 0;
        __syncthreads();
        ls[t] += u;
        __syncthreads();
    }
    if (i < N) ptr[i] = ls[t] - v;
    if (t == 255) bsum[blockIdx.x] = ls[255];
}

__global__ __launch_bounds__(512) void kS2(int* __restrict__ bsum,
                                           int* __restrict__ ptr, int NB, int N) {
    __shared__ int ls[512];
    int t = threadIdx.x;
    int chunk = (NB + 511) / 512;
    int b = t * chunk, e = min(b + chunk, NB);
    int s = 0;
    for (int i = b; i < e; ++i) s += bsum[i];
    ls[t] = s;
    __syncthreads();
    for (int off = 1; off < 512; off <<= 1) {
        int u = (t >= off) ? ls[t - off] : 0;
        __syncthreads();
        ls[t] += u;
        __syncthreads();
    }
    int run = ls[t] - s;
    for (int i = b; i < e; ++i) { int c = bsum[i]; bsum[i] = run; run += c; }
    if (t == 511) ptr[N] = ls[511];
}

__global__ void kS3(int* __restrict__ ptr, int* __restrict__ cnt,
                    const int* __restrict__ bsum, int N) {
    int i = blockIdx.x * 256 + threadIdx.x;
    if (i >= N) return;
    int p = ptr[i] + bsum[blockIdx.x];
    ptr[i] = p;
    cnt[i] = p;
}

__global__ void k_binit(const int* __restrict__ ptr, int* __restrict__ bcur, int nb) {
    int b = blockIdx.x * 256 + threadIdx.x;
    if (b < nb) bcur[b] = ptr[b << 7];
}

// pass A: scatter edge -> its bucket region (sequential within bucket)
__global__ __launch_bounds__(256) void k_passA(
        const int* __restrict__ row, const int* __restrict__ col,
        const float* __restrict__ w, int* __restrict__ bcur,
        int2* __restrict__ tmp, int E) {
    int e = blockIdx.x * 256 + threadIdx.x;
    if (e >= E) return;
    int c = col[e];
    int pos = atomicAdd(&bcur[c >> 7], 1);
    tmp[pos] = make_int2(row[e] | ((c & 127) << 17), __float_as_int(w[e]));
}

// pass B: one block per bucket. LDS cursors place edges at final CSR pos;
// fused degree -> dinv.
__global__ __launch_bounds__(256) void k_passB(
        const int2* __restrict__ tmp, const int* __restrict__ ptr,
        int2* __restrict__ packed, float* __restrict__ dinv, int N) {
    __shared__ int cur[128];
    __shared__ float wsum[128];
    int b = blockIdx.x;
    int node0 = b << 7;
    int node1 = min(node0 + 128, N);
    int t = threadIdx.x;
    if (t < 128) {
        int n = node0 + t;
        cur[t] = (n < node1) ? ptr[n] : 0;
        wsum[t] = 0.0f;
    }
    __syncthreads();
    int beg = ptr[node0], end = ptr[node1];
    for (int k = beg + t; k < end; k += 256) {
        int2 p = tmp[k];
        int li = (p.x >> 17) & 127;
        int r = p.x & 0x1FFFF;
        int pos = atomicAdd(&cur[li], 1);
        packed[pos] = make_int2(r, p.y);
        atomicAdd(&wsum[li], __int_as_float(p.y));
    }
    __syncthreads();
    if (t < 128) {
        int n = node0 + t;
        if (n < node1) {
            float d = 1.0f + wsum[t];
            dinv[n] = d > 0.0f ? rsqrtf(d) : 0.0f;
        }
    }
}

// -------- fallback fill + degw (N too large or ws too small) --------
__global__ void k_fill(const int* __restrict__ row, const int* __restrict__ col,
                       const float* __restrict__ w, int* __restrict__ cursor,
                       int2* __restrict__ packed, int E) {
    int e = blockIdx.x * 256 + threadIdx.x;
    if (e < E) {
        int pos = atomicAdd(&cursor[col[e]], 1);
        packed[pos] = make_int2(row[e], __float_as_int(w[e]));
    }
}

__global__ __launch_bounds__(256) void k_degw(const int2* __restrict__ packed,
                                              const int* __restrict__ ptr,
                                              float* __restrict__ dinv, int N) {
    int wid = (int)(((size_t)blockIdx.x * 256 + threadIdx.x) >> 6);
    int lane = threadIdx.x & 63;
    if (wid >= N) return;
    int beg = ptr[wid], end = ptr[wid + 1];
    float s = 0.0f;
    for (int k = beg + lane; k < end; k += 64) s += __int_as_float(packed[k].y);
#pragma unroll
    for (int off = 32; off; off >>= 1) s += __shfl_xor(s, off);
    if (lane == 0) {
        float d = 1.0f + s;
        dinv[wid] = d > 0.0f ? rsqrtf(d) : 0.0f;
    }
}
// --------------------------------------------------------------------

// bf16-table gather: wave per node, 4 quarters x 1 edge, 16B loads/lane
__global__ __launch_bounds__(256) void k_gatherb(
        const int2* __restrict__ packed, const int* __restrict__ ptr,
        const float* __restrict__ dinv, const unsigned* __restrict__ tab,
        float* __restrict__ out, int N) {
    int wid = (int)(((size_t)blockIdx.x * 256 + threadIdx.x) >> 6);
    int lane = threadIdx.x & 63;
    if (wid >= N) return;
    int c = wid;
    int beg = ptr[c], end = ptr[c + 1];
    float dc = dinv[c];
    int q = lane >> 4;
    int fl = lane & 15;
    float acc[8] = {};
    for (int k = beg; k < end; k += 4) {
        int idx = k + q;
        bool valid = idx < end;
        int2 p = packed[valid ? idx : beg];
        float nrm = valid ? dc * __int_as_float(p.y) * dinv[p.x] : 0.0f;
        uint4 t = *(const uint4*)(tab + (size_t)p.x * 64 + fl * 4);
        acc[0] += nrm * bflo(t.x); acc[1] += nrm * bfhi(t.x);
        acc[2] += nrm * bflo(t.y); acc[3] += nrm * bfhi(t.y);
        acc[4] += nrm * bflo(t.z); acc[5] += nrm * bfhi(t.z);
        acc[6] += nrm * bflo(t.w); acc[7] += nrm * bfhi(t.w);
    }
#pragma unroll
    for (int j = 0; j < 8; ++j) {
        acc[j] += __shfl_xor(acc[j], 16);
        acc[j] += __shfl_xor(acc[j], 32);
    }
    if (q == 0) {
        uint4 t = *(const uint4*)(tab + (size_t)c * 64 + fl * 4);
        float s2 = dc * dc;
        acc[0] += s2 * bflo(t.x); acc[1] += s2 * bfhi(t.x);
        acc[2] += s2 * bflo(t.y); acc[3] += s2 * bfhi(t.y);
        acc[4] += s2 * bflo(t.z); acc[5] += s2 * bfhi(t.z);
        acc[6] += s2 * bflo(t.w); acc[7] += s2 * bfhi(t.w);
        float4* dst = (float4*)(out + (size_t)c * 128 + fl * 8);
        dst[0] = make_float4(acc[0], acc[1], acc[2], acc[3]);
        dst[1] = make_float4(acc[4], acc[5], acc[6], acc[7]);
    }
}

// f32 gather fallback
__global__ __launch_bounds__(256) void k_gather(
        const int2* __restrict__ packed, const int* __restrict__ ptr,
        const float* __restrict__ dinv, const float* __restrict__ nf,
        float* __restrict__ out, int N) {
    int wid = (int)(((size_t)blockIdx.x * 256 + threadIdx.x) >> 6);
    int lane = threadIdx.x & 63;
    if (wid >= N) return;
    int c = wid;
    int beg = ptr[c], end = ptr[c + 1];
    float dc = dinv[c];
    int half = lane >> 5;
    int fl = lane & 31;
    float4 acc = {0.f, 0.f, 0.f, 0.f};
    for (int k = beg; k < end; k += 2) {
        int idx = k + half;
        bool v = idx < end;
        int2 p = packed[v ? idx : beg];
        float nrm = v ? dc * __int_as_float(p.y) * dinv[p.x] : 0.0f;
        float4 x = ((const float4*)(nf + (size_t)p.x * 128))[fl];
        acc.x += nrm * x.x; acc.y += nrm * x.y;
        acc.z += nrm * x.z; acc.w += nrm * x.w;
    }
    acc.x += __shfl_xor(acc.x, 32);
    acc.y += __shfl_xor(acc.y, 32);
    acc.z += __shfl_xor(acc.z, 32);
    acc.w += __shfl_xor(acc.w, 32);
    if (half == 0) {
        float s2 = dc * dc;
        float4 sf = ((const float4*)(nf + (size_t)c * 128))[fl];
        acc.x += s2 * sf.x; acc.y += s2 * sf.y;
        acc.z += s2 * sf.z; acc.w += s2 * sf.w;
        ((float4*)(out + (size_t)c * 128))[fl] = acc;
    }
}

// ---------- atomic-scatter full fallback ----------
__global__ void k_initA(float* __restrict__ deg, float* __restrict__ sums, int N) {
    int i = blockIdx.x * 256 + threadIdx.x;
    if (i < N) deg[i] = 1.0f;
    if (blockIdx.x == 0 && threadIdx.x < 512) sums[threadIdx.x] = 0.0f;
}
__global__ void k_deg(const int* __restrict__ col, const float* __restrict__ w,
                      float* __restrict__ deg, int E) {
    int e = blockIdx.x * 256 + threadIdx.x;
    if (e < E) atomicAdd(&deg[col[e]], w[e]);
}
__global__ void k_dinv(float* __restrict__ deg, int N) {
    int i = blockIdx.x * 256 + threadIdx.x;
    if (i < N) { float d = deg[i]; deg[i] = d > 0.0f ? rsqrtf(d) : 0.0f; }
}
__global__ void k_self(const float* __restrict__ nf, const float* __restrict__ dinv,
                       float* __restrict__ agg, int N) {
    size_t i = (size_t)blockIdx.x * 256 + threadIdx.x;
    if (i >= (size_t)N * 32) return;
    int node = (int)(i >> 5);
    float s = dinv[node]; s = s * s;
    float4 v = ((const float4*)nf)[i];
    v.x *= s; v.y *= s; v.z *= s; v.w *= s;
    ((float4*)agg)[i] = v;
}
__global__ __launch_bounds__(256) void k_scatter(
        const int* __restrict__ row, const int* __restrict__ col,
        const float* __restrict__ w, const float* __restrict__ dinv,
        const float* __restrict__ nf, float* __restrict__ agg, int E) {
    int wid = (int)(((size_t)blockIdx.x * blockDim.x + threadIdx.x) >> 6);
    int lane = threadIdx.x & 63;
    if (wid >= E) return;
    int r = row[wid], c = col[wid];
    float nrm = dinv[r] * w[wid] * dinv[c];
    float2 v = ((const float2*)(nf + (size_t)r * 128))[lane];
    float* dst = agg + (size_t)c * 128 + lane * 2;
    atomicAdd(dst, v.x * nrm);
    atomicAdd(dst + 1, v.y * nrm);
}
// ---------------------------------------------------

// in-place tiled GEMM: h = relu(h @ W + b), fused BN partial sums
__global__ __launch_bounds__(256) void k_gemm2(float* __restrict__ h,
        const float* __restrict__ W, const float* __restrict__ bias,
        float* __restrict__ sums, int N) {
    __shared__ float At[2][32][132];
    __shared__ float Wt[2][32][132];
    int tid = threadIdx.x;
    int tx = tid & 15, ty = tid >> 4;
    int r0 = blockIdx.x * 128;

#define STAGE_A(buf, k0)                                                     \
    _Pragma("unroll")                                                        \
    for (int i = 0; i < 4; ++i) {                                            \
        int idx = tid + 256 * i;                                             \
        int row = idx >> 3, c4 = idx & 7;                                    \
        int gr = r0 + row; if (gr > N - 1) gr = N - 1;                       \
        float4 v = *(const float4*)&h[(size_t)gr * 128 + (k0) + c4 * 4];     \
        At[buf][c4 * 4 + 0][row] = v.x;                                      \
        At[buf][c4 * 4 + 1][row] = v.y;                                      \
        At[buf][c4 * 4 + 2][row] = v.z;                                      \
        At[buf][c4 * 4 + 3][row] = v.w;                                      \
    }
#define STAGE_W(buf, k0)                                                     \
    _Pragma("unroll")                                                        \
    for (int i = 0; i < 4; ++i) {                                            \
        int idx = tid + 256 * i;                                             \
        int kk = idx >> 5, c4 = idx & 31;                                    \
        float4 v = *(const float4*)&W[(size_t)((k0) + kk) * 128 + c4 * 4];   \
        *(float4*)&Wt[buf][kk][c4 * 4] = v;                                  \
    }

    STAGE_A(0, 0)
    STAGE_W(0, 0)
    float acc[8][8] = {};
    for (int t = 0; t < 4; ++t) {
        __syncthreads();
        if (t < 3) {
            int nb = (t + 1) & 1;
            STAGE_A(nb, (t + 1) * 32)
            STAGE_W(nb, (t + 1) * 32)
        }
        int kb = t & 1;
#pragma unroll
        for (int k = 0; k < 32; ++k) {
            float a[8], w[8];
            *(float4*)&a[0] = *(float4*)&At[kb][k][ty * 8];
            *(float4*)&a[4] = *(float4*)&At[kb][k][ty * 8 + 4];
            *(float4*)&w[0] = *(float4*)&Wt[kb][k][tx * 8];
            *(float4*)&w[4] = *(float4*)&Wt[kb][k][tx * 8 + 4];
#pragma unroll
            for (int r = 0; r < 8; ++r)
#pragma unroll
                for (int cc = 0; cc < 8; ++cc)
                    acc[r][cc] += a[r] * w[cc];
        }
    }

    float bv[8];
    *(float4*)&bv[0] = *(const float4*)&bias[tx * 8];
    *(float4*)&bv[4] = *(const float4*)&bias[tx * 8 + 4];
    float s[8] = {}, sq[8] = {};
#pragma unroll
    for (int r = 0; r < 8; ++r) {
        int gr = r0 + ty * 8 + r;
        if (gr < N) {
            float o[8];
#pragma unroll
            for (int cc = 0; cc < 8; ++cc) {
                o[cc] = fmaxf(acc[r][cc] + bv[cc], 0.0f);
                s[cc] += o[cc];
                sq[cc] += o[cc] * o[cc];
            }
            float4* dst = (float4*)&h[(size_t)gr * 128 + tx * 8];
            dst[0] = make_float4(o[0], o[1], o[2], o[3]);
            dst[1] = make_float4(o[4], o[5], o[6], o[7]);
        }
    }
    float* ls = &At[0][0][0];
    __syncthreads();
#pragma unroll
    for (int cc = 0; cc < 8; ++cc) {
        ls[ty * 128 + tx * 8 + cc] = s[cc];
        ls[2048 + ty * 128 + tx * 8 + cc] = sq[cc];
    }
    __syncthreads();
    if (tid < 128) {
        float ssum = 0.f, sqsum = 0.f;
#pragma unroll
        for (int u = 0; u < 16; ++u) {
            ssum += ls[u * 128 + tid];
            sqsum += ls[2048 + u * 128 + tid];
        }
        atomicAdd(&sums[tid], ssum);
        atomicAdd(&sums[128 + tid], sqsum);
    }
#undef STAGE_A
#undef STAGE_W
}

__global__ void k_bnfin(float* __restrict__ sums, const float* __restrict__ gamma,
                        const float* __restrict__ beta, int N) {
    int j = threadIdx.x;
    float inv_n = 1.0f / (float)N;
    float mean = sums[j] * inv_n;
    float var = sums[128 + j] * inv_n - mean * mean;
    float sc = rsqrtf(var + 1e-5f) * gamma[j];
    sums[256 + j] = sc;
    sums[384 + j] = beta[j] - mean * sc;
}

__global__ void k_bnapply(float* __restrict__ h, const float* __restrict__ sums, size_t n4) {
    size_t i = (size_t)blockIdx.x * 256 + threadIdx.x;
    if (i >= n4) return;
    int j4 = (int)(i & 31);
    float4 v = ((float4*)h)[i];
    float4 sc = ((const float4*)(sums + 256))[j4];
    float4 sh = ((const float4*)(sums + 384))[j4];
    v.x = v.x * sc.x + sh.x;
    v.y = v.y * sc.y + sh.y;
    v.z = v.z * sc.z + sh.z;
    v.w = v.w * sc.w + sh.w;
    ((float4*)h)[i] = v;
}

extern "C" void kernel_launch(void* const* d_in, const int* in_sizes, int n_in,
                              void* d_out, int out_size, void* d_ws, size_t ws_size,
                              hipStream_t stream) {
    const float* nf    = (const float*)d_in[0];
    const int*   ei    = (const int*)d_in[1];
    const float* ew    = (const float*)d_in[2];
    const float* W     = (const float*)d_in[3];
    const float* bias  = (const float*)d_in[4];
    const float* gamma = (const float*)d_in[5];
    const float* beta  = (const float*)d_in[6];
    float* out = (float*)d_out;

    const int N = in_sizes[0] / 128;
    const int E = in_sizes[2];
    const int* row = ei;
    const int* col = ei + E;

    int nb_n  = (N + 255) / 256;
    int nb_e  = (E + 255) / 256;
    int nb_w  = (int)(((size_t)N + 3) / 4);
    int nb_v4 = (int)(((size_t)N * 32 + 255) / 256);
    int nbuckets = (N + 127) >> 7;

    // ws layout
    float* dinv = (float*)d_ws;
    int*   ptr  = (int*)d_ws + N;
    int*   cnt  = (int*)d_ws + 2 * N + 1;
    float* sums = (float*)d_ws + 3 * N + 1;
    int*   bsum = (int*)d_ws + 3 * N + 513;
    int*   bcur = (int*)d_ws + 3 * N + 1025;
    size_t pk_off = ((size_t)(3 * N + 1025 + nbuckets) + 3) & ~(size_t)3;
    int2*  packed = (int2*)((int*)d_ws + pk_off);
    size_t tt_off = (pk_off + (size_t)2 * E + 3) & ~(size_t)3;
    int2*  tmp = (int2*)((int*)d_ws + tt_off);
    unsigned* tab = (unsigned*)((int*)d_ws + tt_off);
    size_t tt_words = (size_t)64 * N > (size_t)2 * E ? (size_t)64 * N : (size_t)2 * E;
    size_t need_csr  = (tt_off) * 4;                 // packed only
    size_t need_full = (tt_off + tt_words) * 4;      // + tab/tmp

    if (ws_size >= need_csr) {
        k_init<<<nb_n, 256, 0, stream>>>(cnt, sums, N);
        k_count<<<nb_e, 256, 0, stream>>>(col, cnt, E);
        kS1<<<nb_n, 256, 0, stream>>>(cnt, ptr, bsum, N);
        kS2<<<1, 512, 0, stream>>>(bsum, ptr, nb_n, N);
        kS3<<<nb_n, 256, 0, stream>>>(ptr, cnt, bsum, N);
        bool bucketable = (N <= (1 << 17)) && (ws_size >= need_full);
        if (bucketable) {
            k_binit<<<(nbuckets + 255) / 256, 256, 0, stream>>>(ptr, bcur, nbuckets);
            k_passA<<<nb_e, 256, 0, stream>>>(row, col, ew, bcur, tmp, E);
            k_passB<<<nbuckets, 256, 0, stream>>>(tmp, ptr, packed, dinv, N);
            size_t n8 = (size_t)N * 16;
            k_conv<<<(int)((n8 + 255) / 256), 256, 0, stream>>>(nf, (uint4*)tab, n8);
            k_gatherb<<<nb_w, 256, 0, stream>>>(packed, ptr, dinv, tab, out, N);
        } else if (ws_size >= need_full) {
            size_t n8 = (size_t)N * 16;
            k_conv<<<(int)((n8 + 255) / 256), 256, 0, stream>>>(nf, (uint4*)tab, n8);
            k_fill<<<nb_e, 256, 0, stream>>>(row, col, ew, cnt, packed, E);
            k_degw<<<nb_w, 256, 0, stream>>>(packed, ptr, dinv, N);
            k_gatherb<<<nb_w, 256, 0, stream>>>(packed, ptr, dinv, tab, out, N);
        } else {
            k_fill<<<nb_e, 256, 0, stream>>>(row, col, ew, cnt, packed, E);
            k_degw<<<nb_w, 256, 0, stream>>>(packed, ptr, dinv, N);
            k_gather<<<nb_w, 256, 0, stream>>>(packed, ptr, dinv, nf, out, N);
        }
    } else {
        float* deg = (float*)d_ws;
        sums = (float*)d_ws + N;
        k_initA<<<nb_n, 256, 0, stream>>>(deg, sums, N);
        k_deg<<<nb_e, 256, 0, stream>>>(col, ew, deg, E);
        k_dinv<<<nb_n, 256, 0, stream>>>(deg, N);
        k_self<<<nb_v4, 256, 0, stream>>>(nf, deg, out, N);
        k_scatter<<<(E + 3) / 4, 256, 0, stream>>>(row, col, ew, deg, nf, out, E);
    }
    k_gemm2<<<(N + 127) / 128, 256, 0, stream>>>(out, W, bias, sums, N);
    k_bnfin<<<1, 128, 0, stream>>>(sums, gamma, beta, N);
    k_bnapply<<<nb_v4, 256, 0, stream>>>(out, sums, (size_t)N * 32);
}

// Round 5
// 400.426 us; speedup vs baseline: 3.0722x; 3.0722x over previous
//
#include <hip/hip_runtime.h>
#include <hip/hip_bf16.h>

// GCN layer: h = BN(ReLU(segment_sum(norm * (nf@W))[col] + b))
// Aggregate raw features first (agg[c] = sum norm*nf[row]), then GEMM.
// R1: atomic scatter -> CSR gather.
// R2: bf16 feature table, tiled GEMM + fused BN stats.
// R3: bucket partition, per-edge global cursor atomics -> 747us (4090-way
//     same-address serialization). R4 fix: block-level reservation radix
//     partition (LDS hist + one atomicAdd per block*bucket), and passB
//     derives per-node CSR offsets in-LDS (kills k_count + N-scan + k_degw).
//
// ws layout (4B words):
//   [0, N)               dinv
//   [N, 2N+1)            ptr (CSR offsets)
//   [2N+1, 3N+1)         cnt (fallback fill cursor)
//   [3N+1, 3N+513)       sums (BN: sum, sumsq, scale, shift)
//   [3N+513, 3N+1025)    bsum (fallback scan partials)
//   [3N+1025, +nb+1)     bbase (bucket offsets)
//   [.., +nb)            bcur (bucket cursors)
//   [align4]             packed (E x int2: row, w-bits)
//   [align4]             tmp (passA, E x int2) aliased later by bf16 tab (64N)

#define BKT_BITS 7
#define BKT_SZ 128
#define MAX_BKT 1024        // requires N <= 131072 (row fits 17 bits)
#define CHUNK 8192

__device__ __forceinline__ unsigned bf16rn(float f) {
    unsigned x = __float_as_uint(f);
    return (x + 0x7fffu + ((x >> 16) & 1u)) >> 16;
}
__device__ __forceinline__ float bflo(unsigned u) { return __uint_as_float(u << 16); }
__device__ __forceinline__ float bfhi(unsigned u) { return __uint_as_float(u & 0xffff0000u); }

__global__ void k_init0(int* __restrict__ bcnt, float* __restrict__ sums, int nb) {
    int i = blockIdx.x * 256 + threadIdx.x;
    if (i < nb) bcnt[i] = 0;
    if (blockIdx.x == 0 && threadIdx.x < 512) sums[threadIdx.x] = 0.0f;
}

__global__ void k_conv(const float* __restrict__ nf, uint4* __restrict__ tab, size_t n8) {
    size_t i = (size_t)blockIdx.x * 256 + threadIdx.x;
    if (i >= n8) return;
    const float4* src = (const float4*)nf;
    float4 a = src[2 * i], b = src[2 * i + 1];
    uint4 r;
    r.x = bf16rn(a.x) | (bf16rn(a.y) << 16);
    r.y = bf16rn(a.z) | (bf16rn(a.w) << 16);
    r.z = bf16rn(b.x) | (bf16rn(b.y) << 16);
    r.w = bf16rn(b.z) | (bf16rn(b.w) << 16);
    tab[i] = r;
}

// ---- block-binned bucket histogram ----
__global__ __launch_bounds__(256) void k_bhist(const int* __restrict__ col,
                                               int* __restrict__ bcnt, int E, int nb) {
    __shared__ int h[MAX_BKT];
    for (int i = threadIdx.x; i < nb; i += 256) h[i] = 0;
    __syncthreads();
    int base = blockIdx.x * CHUNK, lim = min(base + CHUNK, E);
    for (int e = base + threadIdx.x; e < lim; e += 256)
        atomicAdd(&h[col[e] >> BKT_BITS], 1);
    __syncthreads();
    for (int i = threadIdx.x; i < nb; i += 256) {
        int c = h[i];
        if (c) atomicAdd(&bcnt[i], c);
    }
}

// single-block scan of bucket counts -> bbase/bcur; also ptr[N]=E
__global__ __launch_bounds__(1024) void k_bscan(const int* __restrict__ bcnt,
        int* __restrict__ bbase, int* __restrict__ bcur,
        int* __restrict__ ptr, int nb, int N, int E) {
    __shared__ int ls[1024];
    int t = threadIdx.x;
    int v = (t < nb) ? bcnt[t] : 0;
    ls[t] = v;
    __syncthreads();
    for (int off = 1; off < 1024; off <<= 1) {
        int u = (t >= off) ? ls[t - off] : 0;
        __syncthreads();
        ls[t] += u;
        __syncthreads();
    }
    if (t < nb) {
        int ex = ls[t] - v;
        bbase[t] = ex;
        bcur[t] = ex;
    }
    if (t == nb - 1) bbase[nb] = ls[t];
    if (t == 0) ptr[N] = E;
}

// pass A: block-level reservation scatter into bucket-grouped tmp
__global__ __launch_bounds__(256) void k_passA2(
        const int* __restrict__ row, const int* __restrict__ col,
        const float* __restrict__ w, int* __restrict__ bcur,
        int2* __restrict__ tmp, int E, int nb) {
    __shared__ int h[MAX_BKT];
    for (int i = threadIdx.x; i < nb; i += 256) h[i] = 0;
    __syncthreads();
    int base = blockIdx.x * CHUNK, lim = min(base + CHUNK, E);
    for (int e = base + threadIdx.x; e < lim; e += 256)
        atomicAdd(&h[col[e] >> BKT_BITS], 1);
    __syncthreads();
    for (int i = threadIdx.x; i < nb; i += 256) {
        int c = h[i];
        if (c) h[i] = atomicAdd(&bcur[i], c);   // reserve block's range
    }
    __syncthreads();
    for (int e = base + threadIdx.x; e < lim; e += 256) {
        int c = col[e];
        int b = c >> BKT_BITS;
        int pos = atomicAdd(&h[b], 1);          // LDS bump within reserved range
        tmp[pos] = make_int2(row[e] | ((c & (BKT_SZ - 1)) << 17), __float_as_int(w[e]));
    }
}

// pass B: per bucket, derive per-node offsets in LDS, place edges into packed,
// fused degree -> dinv and ptr write.
__global__ __launch_bounds__(256) void k_passB2(
        const int2* __restrict__ tmp, const int* __restrict__ bbase,
        int2* __restrict__ packed, int* __restrict__ ptr,
        float* __restrict__ dinv, int N) {
    __shared__ int hcnt[BKT_SZ];
    __shared__ float wsum[BKT_SZ];
    __shared__ int cur[BKT_SZ];
    int b = blockIdx.x;
    int t = threadIdx.x;
    if (t < BKT_SZ) { hcnt[t] = 0; wsum[t] = 0.0f; }
    __syncthreads();
    int beg = bbase[b], end = bbase[b + 1];
    for (int k = beg + t; k < end; k += 256) {
        int2 p = tmp[k];
        int li = (p.x >> 17) & (BKT_SZ - 1);
        atomicAdd(&hcnt[li], 1);
        atomicAdd(&wsum[li], __int_as_float(p.y));
    }
    __syncthreads();
    if (t < BKT_SZ) cur[t] = hcnt[t];
    __syncthreads();
    for (int off = 1; off < BKT_SZ; off <<= 1) {
        int v = (t < BKT_SZ && t >= off) ? cur[t - off] : 0;
        __syncthreads();
        if (t < BKT_SZ) cur[t] += v;
        __syncthreads();
    }
    if (t < BKT_SZ) {
        int p = beg + cur[t] - hcnt[t];   // exclusive
        cur[t] = p;
        int n = (b << BKT_BITS) + t;
        if (n < N) {
            ptr[n] = p;
            float d = 1.0f + wsum[t];
            dinv[n] = d > 0.0f ? rsqrtf(d) : 0.0f;
        }
    }
    __syncthreads();
    for (int k = beg + t; k < end; k += 256) {
        int2 p = tmp[k];
        int li = (p.x >> 17) & (BKT_SZ - 1);
        int pos = atomicAdd(&cur[li], 1);
        packed[pos] = make_int2(p.x & 0x1FFFF, p.y);
    }
}

// bf16-table gather: wave per node, 4 quarters x 1 edge, 16B loads/lane
__global__ __launch_bounds__(256) void k_gatherb(
        const int2* __restrict__ packed, const int* __restrict__ ptr,
        const float* __restrict__ dinv, const unsigned* __restrict__ tab,
        float* __restrict__ out, int N) {
    int wid = (int)(((size_t)blockIdx.x * 256 + threadIdx.x) >> 6);
    int lane = threadIdx.x & 63;
    if (wid >= N) return;
    int c = wid;
    int beg = ptr[c], end = ptr[c + 1];
    float dc = dinv[c];
    int q = lane >> 4;
    int fl = lane & 15;
    float acc[8] = {};
    for (int k = beg; k < end; k += 4) {
        int idx = k + q;
        bool valid = idx < end;
        int2 p = packed[valid ? idx : beg];
        float nrm = valid ? dc * __int_as_float(p.y) * dinv[p.x] : 0.0f;
        uint4 t = *(const uint4*)(tab + (size_t)p.x * 64 + fl * 4);
        acc[0] += nrm * bflo(t.x); acc[1] += nrm * bfhi(t.x);
        acc[2] += nrm * bflo(t.y); acc[3] += nrm * bfhi(t.y);
        acc[4] += nrm * bflo(t.z); acc[5] += nrm * bfhi(t.z);
        acc[6] += nrm * bflo(t.w); acc[7] += nrm * bfhi(t.w);
    }
#pragma unroll
    for (int j = 0; j < 8; ++j) {
        acc[j] += __shfl_xor(acc[j], 16);
        acc[j] += __shfl_xor(acc[j], 32);
    }
    if (q == 0) {
        uint4 t = *(const uint4*)(tab + (size_t)c * 64 + fl * 4);
        float s2 = dc * dc;
        acc[0] += s2 * bflo(t.x); acc[1] += s2 * bfhi(t.x);
        acc[2] += s2 * bflo(t.y); acc[3] += s2 * bfhi(t.y);
        acc[4] += s2 * bflo(t.z); acc[5] += s2 * bfhi(t.z);
        acc[6] += s2 * bflo(t.w); acc[7] += s2 * bfhi(t.w);
        float4* dst = (float4*)(out + (size_t)c * 128 + fl * 8);
        dst[0] = make_float4(acc[0], acc[1], acc[2], acc[3]);
        dst[1] = make_float4(acc[4], acc[5], acc[6], acc[7]);
    }
}

// ---------------- fallback path kernels (ws too small / N too big) ---------
__global__ void k_init(int* __restrict__ cnt, float* __restrict__ sums, int N) {
    int i = blockIdx.x * 256 + threadIdx.x;
    if (i < N) cnt[i] = 0;
    if (blockIdx.x == 0 && threadIdx.x < 512) sums[threadIdx.x] = 0.0f;
}
__global__ void k_count(const int* __restrict__ col, int* __restrict__ cnt, int E) {
    int e = blockIdx.x * 256 + threadIdx.x;
    if (e < E) atomicAdd(&cnt[col[e]], 1);
}
__global__ __launch_bounds__(256) void kS1(const int* __restrict__ cnt,
                                           int* __restrict__ ptr,
                                           int* __restrict__ bsum, int N) {
    __shared__ int ls[256];
    int t = threadIdx.x, i = blockIdx.x * 256 + t;
    int v = (i < N) ? cnt[i] : 0;
    ls[t] = v;
    __syncthreads();
    for (int off = 1; off < 256; off <<= 1) {
        int u = (t >= off) ? ls[t - off] : 0;
        __syncthreads();
        ls[t] += u;
        __syncthreads();
    }
    if (i < N) ptr[i] = ls[t] - v;
    if (t == 255) bsum[blockIdx.x] = ls[255];
}
__global__ __launch_bounds__(512) void kS2(int* __restrict__ bsum,
                                           int* __restrict__ ptr, int NB, int N) {
    __shared__ int ls[512];
    int t = threadIdx.x;
    int chunk = (NB + 511) / 512;
    int b = t * chunk, e = min(b + chunk, NB);
    int s = 0;
    for (int i = b; i < e; ++i) s += bsum[i];
    ls[t] = s;
    __syncthreads();
    for (int off = 1; off < 512; off <<= 1) {
        int u = (t >= off) ? ls[t - off] : 0;
        __syncthreads();
        ls[t] += u;
        __syncthreads();
    }
    int run = ls[t] - s;
    for (int i = b; i < e; ++i) { int c = bsum[i]; bsum[i] = run; run += c; }
    if (t == 511) ptr[N] = ls[511];
}
__global__ void kS3(int* __restrict__ ptr, int* __restrict__ cnt,
                    const int* __restrict__ bsum, int N) {
    int i = blockIdx.x * 256 + threadIdx.x;
    if (i >= N) return;
    int p = ptr[i] + bsum[blockIdx.x];
    ptr[i] = p;
    cnt[i] = p;
}
__global__ void k_fill(const int* __restrict__ row, const int* __restrict__ col,
                       const float* __restrict__ w, int* __restrict__ cursor,
                       int2* __restrict__ packed, int E) {
    int e = blockIdx.x * 256 + threadIdx.x;
    if (e < E) {
        int pos = atomicAdd(&cursor[col[e]], 1);
        packed[pos] = make_int2(row[e], __float_as_int(w[e]));
    }
}
__global__ __launch_bounds__(256) void k_degw(const int2* __restrict__ packed,
                                              const int* __restrict__ ptr,
                                              float* __restrict__ dinv, int N) {
    int wid = (int)(((size_t)blockIdx.x * 256 + threadIdx.x) >> 6);
    int lane = threadIdx.x & 63;
    if (wid >= N) return;
    int beg = ptr[wid], end = ptr[wid + 1];
    float s = 0.0f;
    for (int k = beg + lane; k < end; k += 64) s += __int_as_float(packed[k].y);
#pragma unroll
    for (int off = 32; off; off >>= 1) s += __shfl_xor(s, off);
    if (lane == 0) {
        float d = 1.0f + s;
        dinv[wid] = d > 0.0f ? rsqrtf(d) : 0.0f;
    }
}
__global__ __launch_bounds__(256) void k_gather(
        const int2* __restrict__ packed, const int* __restrict__ ptr,
        const float* __restrict__ dinv, const float* __restrict__ nf,
        float* __restrict__ out, int N) {
    int wid = (int)(((size_t)blockIdx.x * 256 + threadIdx.x) >> 6);
    int lane = threadIdx.x & 63;
    if (wid >= N) return;
    int c = wid;
    int beg = ptr[c], end = ptr[c + 1];
    float dc = dinv[c];
    int half = lane >> 5;
    int fl = lane & 31;
    float4 acc = {0.f, 0.f, 0.f, 0.f};
    for (int k = beg; k < end; k += 2) {
        int idx = k + half;
        bool v = idx < end;
        int2 p = packed[v ? idx : beg];
        float nrm = v ? dc * __int_as_float(p.y) * dinv[p.x] : 0.0f;
        float4 x = ((const float4*)(nf + (size_t)p.x * 128))[fl];
        acc.x += nrm * x.x; acc.y += nrm * x.y;
        acc.z += nrm * x.z; acc.w += nrm * x.w;
    }
    acc.x += __shfl_xor(acc.x, 32);
    acc.y += __shfl_xor(acc.y, 32);
    acc.z += __shfl_xor(acc.z, 32);
    acc.w += __shfl_xor(acc.w, 32);
    if (half == 0) {
        float s2 = dc * dc;
        float4 sf = ((const float4*)(nf + (size_t)c * 128))[fl];
        acc.x += s2 * sf.x; acc.y += s2 * sf.y;
        acc.z += s2 * sf.z; acc.w += s2 * sf.w;
        ((float4*)(out + (size_t)c * 128))[fl] = acc;
    }
}
__global__ void k_initA(float* __restrict__ deg, float* __restrict__ sums, int N) {
    int i = blockIdx.x * 256 + threadIdx.x;
    if (i < N) deg[i] = 1.0f;
    if (blockIdx.x == 0 && threadIdx.x < 512) sums[threadIdx.x] = 0.0f;
}
__global__ void k_deg(const int* __restrict__ col, const float* __restrict__ w,
                      float* __restrict__ deg, int E) {
    int e = blockIdx.x * 256 + threadIdx.x;
    if (e < E) atomicAdd(&deg[col[e]], w[e]);
}
__global__ void k_dinv(float* __restrict__ deg, int N) {
    int i = blockIdx.x * 256 + threadIdx.x;
    if (i < N) { float d = deg[i]; deg[i] = d > 0.0f ? rsqrtf(d) : 0.0f; }
}
__global__ void k_self(const float* __restrict__ nf, const float* __restrict__ dinv,
                       float* __restrict__ agg, int N) {
    size_t i = (size_t)blockIdx.x * 256 + threadIdx.x;
    if (i >= (size_t)N * 32) return;
    int node = (int)(i >> 5);
    float s = dinv[node]; s = s * s;
    float4 v = ((const float4*)nf)[i];
    v.x *= s; v.y *= s; v.z *= s; v.w *= s;
    ((float4*)agg)[i] = v;
}
__global__ __launch_bounds__(256) void k_scatter(
        const int* __restrict__ row, const int* __restrict__ col,
        const float* __restrict__ w, const float* __restrict__ dinv,
        const float* __restrict__ nf, float* __restrict__ agg, int E) {
    int wid = (int)(((size_t)blockIdx.x * blockDim.x + threadIdx.x) >> 6);
    int lane = threadIdx.x & 63;
    if (wid >= E) return;
    int r = row[wid], c = col[wid];
    float nrm = dinv[r] * w[wid] * dinv[c];
    float2 v = ((const float2*)(nf + (size_t)r * 128))[lane];
    float* dst = agg + (size_t)c * 128 + lane * 2;
    atomicAdd(dst, v.x * nrm);
    atomicAdd(dst + 1, v.y * nrm);
}
// ---------------------------------------------------------------------------

// in-place tiled GEMM: h = relu(h @ W + b), fused BN partial sums
__global__ __launch_bounds__(256) void k_gemm2(float* __restrict__ h,
        const float* __restrict__ W, const float* __restrict__ bias,
        float* __restrict__ sums, int N) {
    __shared__ float At[2][32][132];
    __shared__ float Wt[2][32][132];
    int tid = threadIdx.x;
    int tx = tid & 15, ty = tid >> 4;
    int r0 = blockIdx.x * 128;

#define STAGE_A(buf, k0)                                                     \
    _Pragma("unroll")                                                        \
    for (int i = 0; i < 4; ++i) {                                            \
        int idx = tid + 256 * i;                                             \
        int row = idx >> 3, c4 = idx & 7;                                    \
        int gr = r0 + row; if (gr > N - 1) gr = N - 1;                       \
        float4 v = *(const float4*)&h[(size_t)gr * 128 + (k0) + c4 * 4];     \
        At[buf][c4 * 4 + 0][row] = v.x;                                      \
        At[buf][c4 * 4 + 1][row] = v.y;                                      \
        At[buf][c4 * 4 + 2][row] = v.z;                                      \
        At[buf][c4 * 4 + 3][row] = v.w;                                      \
    }
#define STAGE_W(buf, k0)                                                     \
    _Pragma("unroll")                                                        \
    for (int i = 0; i < 4; ++i) {                                            \
        int idx = tid + 256 * i;                                             \
        int kk = idx >> 5, c4 = idx & 31;                                    \
        float4 v = *(const float4*)&W[(size_t)((k0) + kk) * 128 + c4 * 4];   \
        *(float4*)&Wt[buf][kk][c4 * 4] = v;                                  \
    }

    STAGE_A(0, 0)
    STAGE_W(0, 0)
    float acc[8][8] = {};
    for (int t = 0; t < 4; ++t) {
        __syncthreads();
        if (t < 3) {
            int nb = (t + 1) & 1;
            STAGE_A(nb, (t + 1) * 32)
            STAGE_W(nb, (t + 1) * 32)
        }
        int kb = t & 1;
#pragma unroll
        for (int k = 0; k < 32; ++k) {
            float a[8], w[8];
            *(float4*)&a[0] = *(float4*)&At[kb][k][ty * 8];
            *(float4*)&a[4] = *(float4*)&At[kb][k][ty * 8 + 4];
            *(float4*)&w[0] = *(float4*)&Wt[kb][k][tx * 8];
            *(float4*)&w[4] = *(float4*)&Wt[kb][k][tx * 8 + 4];
#pragma unroll
            for (int r = 0; r < 8; ++r)
#pragma unroll
                for (int cc = 0; cc < 8; ++cc)
                    acc[r][cc] += a[r] * w[cc];
        }
    }

    float bv[8];
    *(float4*)&bv[0] = *(const float4*)&bias[tx * 8];
    *(float4*)&bv[4] = *(const float4*)&bias[tx * 8 + 4];
    float s[8] = {}, sq[8] = {};
#pragma unroll
    for (int r = 0; r < 8; ++r) {
        int gr = r0 + ty * 8 + r;
        if (gr < N) {
            float o[8];
#pragma unroll
            for (int cc = 0; cc < 8; ++cc) {
                o[cc] = fmaxf(acc[r][cc] + bv[cc], 0.0f);
                s[cc] += o[cc];
                sq[cc] += o[cc] * o[cc];
            }
            float4* dst = (float4*)&h[(size_t)gr * 128 + tx * 8];
            dst[0] = make_float4(o[0], o[1], o[2], o[3]);
            dst[1] = make_float4(o[4], o[5], o[6], o[7]);
        }
    }
    float* ls = &At[0][0][0];
    __syncthreads();
#pragma unroll
    for (int cc = 0; cc < 8; ++cc) {
        ls[ty * 128 + tx * 8 + cc] = s[cc];
        ls[2048 + ty * 128 + tx * 8 + cc] = sq[cc];
    }
    __syncthreads();
    if (tid < 128) {
        float ssum = 0.f, sqsum = 0.f;
#pragma unroll
        for (int u = 0; u < 16; ++u) {
            ssum += ls[u * 128 + tid];
            sqsum += ls[2048 + u * 128 + tid];
        }
        atomicAdd(&sums[tid], ssum);
        atomicAdd(&sums[128 + tid], sqsum);
    }
#undef STAGE_A
#undef STAGE_W
}

__global__ void k_bnfin(float* __restrict__ sums, const float* __restrict__ gamma,
                        const float* __restrict__ beta, int N) {
    int j = threadIdx.x;
    float inv_n = 1.0f / (float)N;
    float mean = sums[j] * inv_n;
    float var = sums[128 + j] * inv_n - mean * mean;
    float sc = rsqrtf(var + 1e-5f) * gamma[j];
    sums[256 + j] = sc;
    sums[384 + j] = beta[j] - mean * sc;
}

__global__ void k_bnapply(float* __restrict__ h, const float* __restrict__ sums, size_t n4) {
    size_t i = (size_t)blockIdx.x * 256 + threadIdx.x;
    if (i >= n4) return;
    int j4 = (int)(i & 31);
    float4 v = ((float4*)h)[i];
    float4 sc = ((const float4*)(sums + 256))[j4];
    float4 sh = ((const float4*)(sums + 384))[j4];
    v.x = v.x * sc.x + sh.x;
    v.y = v.y * sc.y + sh.y;
    v.z = v.z * sc.z + sh.z;
    v.w = v.w * sc.w + sh.w;
    ((float4*)h)[i] = v;
}

extern "C" void kernel_launch(void* const* d_in, const int* in_sizes, int n_in,
                              void* d_out, int out_size, void* d_ws, size_t ws_size,
                              hipStream_t stream) {
    const float* nf    = (const float*)d_in[0];
    const int*   ei    = (const int*)d_in[1];
    const float* ew    = (const float*)d_in[2];
    const float* W     = (const float*)d_in[3];
    const float* bias  = (const float*)d_in[4];
    const float* gamma = (const float*)d_in[5];
    const float* beta  = (const float*)d_in[6];
    float* out = (float*)d_out;

    const int N = in_sizes[0] / 128;
    const int E = in_sizes[2];
    const int* row = ei;
    const int* col = ei + E;

    int nb_n  = (N + 255) / 256;
    int nb_e  = (E + 255) / 256;
    int nb_w  = (int)(((size_t)N + 3) / 4);
    int nb_v4 = (int)(((size_t)N * 32 + 255) / 256);
    int nbk   = (N + BKT_SZ - 1) >> BKT_BITS;
    int nb_c  = (E + CHUNK - 1) / CHUNK;

    // ws layout
    float* dinv = (float*)d_ws;
    int*   ptr  = (int*)d_ws + N;
    int*   cnt  = (int*)d_ws + 2 * N + 1;
    float* sums = (float*)d_ws + 3 * N + 1;
    int*   bsum = (int*)d_ws + 3 * N + 513;
    int*   bbase = (int*)d_ws + 3 * N + 1025;
    int*   bcur  = bbase + nbk + 1;
    size_t pk_off = ((size_t)(3 * N + 1026 + 2 * nbk) + 3) & ~(size_t)3;
    int2*  packed = (int2*)((int*)d_ws + pk_off);
    size_t tt_off = (pk_off + (size_t)2 * E + 3) & ~(size_t)3;
    int2*  tmp = (int2*)((int*)d_ws + tt_off);
    unsigned* tab = (unsigned*)((int*)d_ws + tt_off);
    size_t tt_words = (size_t)64 * N > (size_t)2 * E ? (size_t)64 * N : (size_t)2 * E;
    size_t need_csr  = tt_off * 4;
    size_t need_full = (tt_off + tt_words) * 4;

    bool bucketable = (nbk <= MAX_BKT) && (ws_size >= need_full);
    if (bucketable) {
        k_init0<<<(max(nbk, 512) + 255) / 256, 256, 0, stream>>>(bbase + nbk + 1, sums, nbk);  // zero bcur? no: bcnt
        // NOTE: use bcur array as bcnt for histogram, then bscan turns it into cursors
        k_bhist<<<nb_c, 256, 0, stream>>>(col, bcur, E, nbk);
        k_bscan<<<1, 1024, 0, stream>>>(bcur, bbase, bcur, ptr, nbk, N, E);
        k_passA2<<<nb_c, 256, 0, stream>>>(row, col, ew, bcur, tmp, E, nbk);
        k_passB2<<<nbk, 256, 0, stream>>>(tmp, bbase, packed, ptr, dinv, N);
        size_t n8 = (size_t)N * 16;
        k_conv<<<(int)((n8 + 255) / 256), 256, 0, stream>>>(nf, (uint4*)tab, n8);
        k_gatherb<<<nb_w, 256, 0, stream>>>(packed, ptr, dinv, tab, out, N);
    } else if (ws_size >= need_csr) {
        k_init<<<nb_n, 256, 0, stream>>>(cnt, sums, N);
        k_count<<<nb_e, 256, 0, stream>>>(col, cnt, E);
        kS1<<<nb_n, 256, 0, stream>>>(cnt, ptr, bsum, N);
        kS2<<<1, 512, 0, stream>>>(bsum, ptr, nb_n, N);
        kS3<<<nb_n, 256, 0, stream>>>(ptr, cnt, bsum, N);
        if (ws_size >= need_full) {
            size_t n8 = (size_t)N * 16;
            k_conv<<<(int)((n8 + 255) / 256), 256, 0, stream>>>(nf, (uint4*)tab, n8);
            k_fill<<<nb_e, 256, 0, stream>>>(row, col, ew, cnt, packed, E);
            k_degw<<<nb_w, 256, 0, stream>>>(packed, ptr, dinv, N);
            k_gatherb<<<nb_w, 256, 0, stream>>>(packed, ptr, dinv, tab, out, N);
        } else {
            k_fill<<<nb_e, 256, 0, stream>>>(row, col, ew, cnt, packed, E);
            k_degw<<<nb_w, 256, 0, stream>>>(packed, ptr, dinv, N);
            k_gather<<<nb_w, 256, 0, stream>>>(packed, ptr, dinv, nf, out, N);
        }
    } else {
        float* deg = (float*)d_ws;
        sums = (float*)d_ws + N;
        k_initA<<<nb_n, 256, 0, stream>>>(deg, sums, N);
        k_deg<<<nb_e, 256, 0, stream>>>(col, ew, deg, E);
        k_dinv<<<nb_n, 256, 0, stream>>>(deg, N);
        k_self<<<nb_v4, 256, 0, stream>>>(nf, deg, out, N);
        k_scatter<<<(E + 3) / 4, 256, 0, stream>>>(row, col, ew, deg, nf, out, E);
    }
    k_gemm2<<<(N + 127) / 128, 256, 0, stream>>>(out, W, bias, sums, N);
    k_bnfin<<<1, 128, 0, stream>>>(sums, gamma, beta, N);
    k_bnapply<<<nb_v4, 256, 0, stream>>>(out, sums, (size_t)N * 32);
}